// Round 8
// baseline (505.006 us; speedup 1.0000x reference)
//
#include <hip/hip_runtime.h>
#include <cstdint>
#include <cstddef>

// ---------------------------------------------------------------------------
// HarmonicTransformerLayer  B=2 S=2048 D=1024 H=16 HD=64 F=4096
// Round 8 (= round-7 kernel, resubmitted after two acquisition timeouts):
//   - gemm_bt8: 256x256 tile, BK=64, 8 waves, counted-vmcnt 2-tile-deep
//     pipeline (raw s_barrier + s_waitcnt vmcnt(8), never 0 in steady state),
//     setprio around MFMA clusters. Used for QKV + FFN-up.
//   - Wo / FFN-down keep 2-phase 128^2 gemm_bt; attn unchanged from round 5.
// ---------------------------------------------------------------------------

typedef float  f32x4  __attribute__((ext_vector_type(4)));
typedef __bf16 bf16x8 __attribute__((ext_vector_type(8)));
typedef unsigned short u16x8 __attribute__((ext_vector_type(8)));
typedef unsigned short u16x4 __attribute__((ext_vector_type(4)));
typedef unsigned int   u32x2 __attribute__((ext_vector_type(2)));
typedef unsigned int   u32x4 __attribute__((ext_vector_type(4)));

#define MFMA_BF16(a, b, c) __builtin_amdgcn_mfma_f32_16x16x32_bf16((a), (b), (c), 0, 0, 0)

static __device__ __forceinline__ unsigned short f32_to_bf16(float f) {
  return __builtin_bit_cast(unsigned short, (__bf16)f);   // HW RNE cvt on gfx950
}
static __device__ __forceinline__ bf16x8 lds_frag(const unsigned short* base, int byte) {
  return __builtin_bit_cast(bf16x8, *(const u16x8*)((const char*)base + byte));
}
static __device__ __forceinline__ float spectral_act(float x) {
  const float c = 0.7978845608028654f;      // sqrt(2/pi)
  float g = 0.5f * x * (1.0f + tanhf(c * (x + 0.044715f * x * x * x)));
  return g + 0.5f * __sinf(x);              // ALPHA=0.5, BETA=1.0
}
static __device__ __forceinline__ void gload_lds16(const void* g, void* lds) {
  __builtin_amdgcn_global_load_lds((const __attribute__((address_space(1))) unsigned int*)g,
                                   (__attribute__((address_space(3))) unsigned int*)lds,
                                   16, 0, 0);
}
static __device__ __forceinline__ u32x2 tr_read(unsigned addr) {
  u32x2 r;
  asm volatile("ds_read_b64_tr_b16 %0, %1" : "=v"(r) : "v"(addr));
  return r;
}

// ---------------------------------------------------------------------------
// fp32 -> bf16 vector convert
// ---------------------------------------------------------------------------
__global__ __launch_bounds__(256) void cvt_f32_bf16(const float* __restrict__ in,
                                                    unsigned short* __restrict__ out, int n) {
  int i = (blockIdx.x * 256 + threadIdx.x) * 4;
  if (i < n) {
    float4 v = *(const float4*)(in + i);
    u16x4 o;
    o[0] = f32_to_bf16(v.x); o[1] = f32_to_bf16(v.y);
    o[2] = f32_to_bf16(v.z); o[3] = f32_to_bf16(v.w);
    *(u16x4*)(out + i) = o;
  }
}

// ---------------------------------------------------------------------------
// W [K][N] fp32  ->  Wt [N][K] bf16   (32x32 LDS tile transpose)
// ---------------------------------------------------------------------------
__global__ __launch_bounds__(256) void transpose_f32_bf16(const float* __restrict__ W,
                                                          unsigned short* __restrict__ Wt,
                                                          int K, int N) {
  __shared__ float tile[32][33];
  int tx = threadIdx.x & 31, ty = threadIdx.x >> 5;   // 32 x 8
  int k0 = blockIdx.y * 32, n0 = blockIdx.x * 32;
#pragma unroll
  for (int i = 0; i < 4; i++)
    tile[ty + i * 8][tx] = W[(size_t)(k0 + ty + i * 8) * N + n0 + tx];
  __syncthreads();
#pragma unroll
  for (int i = 0; i < 4; i++)
    Wt[(size_t)(n0 + ty + i * 8) * K + k0 + tx] = f32_to_bf16(tile[tx][ty + i * 8]);
}

// ---------------------------------------------------------------------------
// 8-wave 256^2 GEMM: C[M,N] = A[M,K] @ Bt[N,K]^T + bias.  BK=64.
// 512 threads = 8 waves (2M x 4N), per-wave tile 128x64, acc 8x4 frags.
// LDS 128KB: As[2][256][64], Bs[2][256][64]; linear 128B rows, content
// chunk c stored at position c^(row&7) via pre-swizzled global source.
// Pipeline: 2 K-tiles in flight; per K-tile: compute (setprio around MFMA)
// -> lgkmcnt(0)+s_barrier -> stage(t+2) -> vmcnt(8) -> s_barrier.
// EPI 0: bf16 out, 2: spectral(act) -> bf16 out.
// ---------------------------------------------------------------------------
template <int EPI>
__global__ __launch_bounds__(512, 2) void gemm_bt8(const unsigned short* __restrict__ Ag,
                                                   const unsigned short* __restrict__ Bt,
                                                   const float* __restrict__ bias,
                                                   unsigned short* __restrict__ Cb,
                                                   float* __restrict__ Cf,
                                                   int M, int N, int K) {
  __shared__ unsigned short As[2][256 * 64];
  __shared__ unsigned short Bs[2][256 * 64];
  const int t = threadIdx.x;
  const int lane = t & 63, w = t >> 6;
  const int wr = w >> 2, wc = w & 3;            // 2 x 4 wave grid
  const int g = lane >> 4, cc = lane & 15;
  const int row0 = blockIdx.y * 256, col0 = blockIdx.x * 256;

  f32x4 acc[8][4];
#pragma unroll
  for (int mi = 0; mi < 8; mi++)
#pragma unroll
    for (int ni = 0; ni < 4; ni++) acc[mi][ni] = (f32x4){0.f, 0.f, 0.f, 0.f};

  const int nk = K >> 6;

  // staging: thread t covers row (i*64 + w*8 + (lane>>3)), 16B chunk (lane&7).
  // linear LDS dest: wave base + lane*16 == row*128 + (lane&7)*16. source
  // chunk pre-swizzled: sc = (lane&7) ^ (row&7).
  const int sro = w * 8 + (lane >> 3);
  const int sc8 = ((lane & 7) ^ ((lane >> 3) & 7)) * 8;   // element offset

  auto stage = [&](int buf, int kt) {
#pragma unroll
    for (int i = 0; i < 4; ++i) {
      int r = i * 64 + sro;
      gload_lds16(Ag + (size_t)(row0 + r) * K + (kt << 6) + sc8,
                  &As[buf][(i * 64 + w * 8) * 64]);
    }
#pragma unroll
    for (int i = 0; i < 4; ++i) {
      int r = i * 64 + sro;
      gload_lds16(Bt + (size_t)(col0 + r) * K + (kt << 6) + sc8,
                  &Bs[buf][(i * 64 + w * 8) * 64]);
    }
  };

  stage(0, 0);
  if (nk > 1) {
    stage(1, 1);
    asm volatile("s_waitcnt vmcnt(8)" ::: "memory");   // tile0 landed, tile1 in flight
  } else {
    asm volatile("s_waitcnt vmcnt(0)" ::: "memory");
  }
  asm volatile("s_barrier" ::: "memory");

  int cur = 0;
  for (int kt = 0; kt < nk; ++kt) {
    // ---- compute tile kt from buf[cur]: 4 quadrant phases of 16 MFMA ----
#pragma unroll
    for (int qm = 0; qm < 2; ++qm) {
      bf16x8 a[2][4];
#pragma unroll
      for (int ks = 0; ks < 2; ++ks)
#pragma unroll
        for (int i = 0; i < 4; ++i) {
          int r = wr * 128 + (qm * 4 + i) * 16 + cc;
          a[ks][i] = lds_frag(&As[cur][0], r * 128 + (((ks * 4 + g) ^ (cc & 7)) << 4));
        }
#pragma unroll
      for (int qn = 0; qn < 2; ++qn) {
        bf16x8 bb[2][2];
#pragma unroll
        for (int ks = 0; ks < 2; ++ks)
#pragma unroll
          for (int j = 0; j < 2; ++j) {
            int r = wc * 64 + (qn * 2 + j) * 16 + cc;
            bb[ks][j] = lds_frag(&Bs[cur][0], r * 128 + (((ks * 4 + g) ^ (cc & 7)) << 4));
          }
        __builtin_amdgcn_s_setprio(1);
#pragma unroll
        for (int ks = 0; ks < 2; ++ks)
#pragma unroll
          for (int i = 0; i < 4; ++i)
#pragma unroll
            for (int j = 0; j < 2; ++j)
              acc[qm * 4 + i][qn * 2 + j] =
                  MFMA_BF16(a[ks][i], bb[ks][j], acc[qm * 4 + i][qn * 2 + j]);
        __builtin_amdgcn_s_setprio(0);
      }
    }
    if (kt == nk - 1) break;
    // ---- sync + stage tile kt+2 into the buffer we just finished ----
    // lgkmcnt(0): all ds_reads of buf[cur] SERVICED before any wave can
    // cross the barrier and overwrite it (rule #18: MFMA sinking could
    // otherwise leave reads in flight). sched_barrier pins it.
    asm volatile("s_waitcnt lgkmcnt(0)" ::: "memory");
    __builtin_amdgcn_sched_barrier(0);
    asm volatile("s_barrier" ::: "memory");            // all waves done reading cur
    if (kt + 2 < nk) {
      stage(cur, kt + 2);
      asm volatile("s_waitcnt vmcnt(8)" ::: "memory"); // own t+1 loads landed
    } else {
      asm volatile("s_waitcnt vmcnt(0)" ::: "memory"); // tail: drain t+1
    }
    asm volatile("s_barrier" ::: "memory");            // everyone's t+1 landed
    cur ^= 1;
  }

  // ---- epilogue ----
#pragma unroll
  for (int mi = 0; mi < 8; ++mi) {
#pragma unroll
    for (int ni = 0; ni < 4; ++ni) {
      int col = col0 + wc * 64 + ni * 16 + cc;
      float bv = bias[col];
#pragma unroll
      for (int r4 = 0; r4 < 4; r4++) {
        int row = row0 + wr * 128 + mi * 16 + g * 4 + r4;
        float val = acc[mi][ni][r4] + bv;
        if (EPI == 2) val = spectral_act(val);
        if (EPI == 0 || EPI == 2) Cb[(size_t)row * N + col] = f32_to_bf16(val);
        else                      Cf[(size_t)row * N + col] = val;
      }
    }
  }
}

// ---------------------------------------------------------------------------
// 2-phase 128-tile GEMM (round-5) for N=1024 outputs (Wo, FFN-down).
// ---------------------------------------------------------------------------
template <int BM, int BN, int EPI>
__global__ __launch_bounds__(256) void gemm_bt(const unsigned short* __restrict__ A,
                                               const unsigned short* __restrict__ Bt,
                                               const float* __restrict__ bias,
                                               unsigned short* __restrict__ Cb,
                                               float* __restrict__ Cf,
                                               int M, int N, int K) {
  constexpr int MI = BM / 32;
  constexpr int NI = BN / 32;
  __shared__ unsigned short As[2][BM * 32];
  __shared__ unsigned short Bs[2][BN * 32];
  const int t = threadIdx.x;
  const int lane = t & 63, w = t >> 6;
  const int wr = w >> 1, wc = w & 1;
  const int g = lane >> 4, cc = lane & 15;
  const int row0 = blockIdx.y * BM, col0 = blockIdx.x * BN;

  f32x4 acc[MI][NI];
#pragma unroll
  for (int mi = 0; mi < MI; mi++)
#pragma unroll
    for (int ni = 0; ni < NI; ni++) acc[mi][ni] = (f32x4){0.f, 0.f, 0.f, 0.f};

  const int nk = K >> 5;
  const int srow = lane >> 2;
  const int schunk = (lane & 3) ^ (srow & 3);

  auto stage = [&](int buf, int kt) {
#pragma unroll
    for (int i = 0; i < BM / 64; ++i) {
      int r = i * 64 + w * 16;
      gload_lds16(A + (size_t)(row0 + r + srow) * K + (kt << 5) + schunk * 8,
                  &As[buf][r * 32]);
    }
#pragma unroll
    for (int i = 0; i < BN / 64; ++i) {
      int r = i * 64 + w * 16;
      gload_lds16(Bt + (size_t)(col0 + r + srow) * K + (kt << 5) + schunk * 8,
                  &Bs[buf][r * 32]);
    }
  };

  stage(0, 0);
  __syncthreads();
  int cur = 0;
  for (int kt = 0; kt < nk; ++kt) {
    if (kt + 1 < nk) stage(cur ^ 1, kt + 1);

    bf16x8 af[MI], bg[NI];
#pragma unroll
    for (int mi = 0; mi < MI; mi++) {
      int r = wr * (BM / 2) + mi * 16 + cc;
      af[mi] = lds_frag(&As[cur][0], r * 64 + ((g ^ (cc & 3)) << 4));
    }
#pragma unroll
    for (int ni = 0; ni < NI; ni++) {
      int r = wc * (BN / 2) + ni * 16 + cc;
      bg[ni] = lds_frag(&Bs[cur][0], r * 64 + ((g ^ (cc & 3)) << 4));
    }
#pragma unroll
    for (int mi = 0; mi < MI; mi++)
#pragma unroll
      for (int ni = 0; ni < NI; ni++)
        acc[mi][ni] = MFMA_BF16(af[mi], bg[ni], acc[mi][ni]);

    __syncthreads();
    cur ^= 1;
  }

#pragma unroll
  for (int mi = 0; mi < MI; mi++) {
#pragma unroll
    for (int ni = 0; ni < NI; ni++) {
      int col = col0 + wc * (BN / 2) + ni * 16 + cc;
      float bv = bias[col];
#pragma unroll
      for (int r4 = 0; r4 < 4; r4++) {
        int row = row0 + wr * (BM / 2) + mi * 16 + g * 4 + r4;
        float val = acc[mi][ni][r4] + bv;
        if (EPI == 2) val = spectral_act(val);
        if (EPI == 0 || EPI == 2) Cb[(size_t)row * N + col] = f32_to_bf16(val);
        else                      Cf[(size_t)row * N + col] = val;
      }
    }
  }
}

// ---------------------------------------------------------------------------
// Flash attention with harmonic score modification (round-5, T14 split).
// ---------------------------------------------------------------------------
__global__ __launch_bounds__(256) void attn_fused(const unsigned short* __restrict__ Qb,
                                                  const unsigned short* __restrict__ Kb,
                                                  const unsigned short* __restrict__ Vb,
                                                  int ld,
                                                  const float* __restrict__ resonance,
                                                  const float* __restrict__ phase,
                                                  unsigned short* __restrict__ O, int ldo) {
  constexpr int S = 2048;
  __shared__ unsigned short Ks[64 * 64];
  __shared__ unsigned short Vs[4][64 * 16];
  __shared__ unsigned short Ps[4][16 * 64];

  const int t = threadIdx.x, lane = t & 63, w = t >> 6;
  const int g = lane >> 4, cc = lane & 15;
  const int bh = blockIdx.y, b = bh >> 4, h = bh & 15;
  const int q0 = blockIdx.x * 64 + w * 16;
  const float res = resonance[h], ph = phase[h];

  const unsigned short* Qh = Qb + (size_t)b * S * ld + h * 64;
  const unsigned short* Kh = Kb + (size_t)b * S * ld + h * 64;
  const unsigned short* Vh = Vb + (size_t)b * S * ld + h * 64;

  bf16x8 qa0, qa1;
  {
    const unsigned short* qp = Qh + (size_t)(q0 + cc) * ld + g * 8;
    qa0 = __builtin_bit_cast(bf16x8, *(const u16x8*)qp);
    qa1 = __builtin_bit_cast(bf16x8, *(const u16x8*)(qp + 32));
  }

  bf16x8 ones8;
#pragma unroll
  for (int j = 0; j < 8; j++) ones8[j] = (__bf16)1.0f;

  const int krow = t >> 3, kc8 = (t & 7) * 8;
  const int vkey = t & 63, vb0 = (t >> 6) * 16;
  u16x8 kr0, kr1, vr0, vr1;

  auto issue_loads = [&](int kt) {
    const unsigned short* kp = Kh + (size_t)(kt * 64) * ld;
    kr0 = *(const u16x8*)(kp + (size_t)krow * ld + kc8);
    kr1 = *(const u16x8*)(kp + (size_t)(krow + 32) * ld + kc8);
    const unsigned short* vp = Vh + (size_t)(kt * 64 + vkey) * ld + vb0;
    vr0 = *(const u16x8*)vp;
    vr1 = *(const u16x8*)(vp + 8);
  };
  auto stage_lds = [&]() {
    *(u16x8*)((char*)Ks + ((krow * 128 + kc8 * 2) ^ ((krow & 7) << 4))) = kr0;
    int row2 = krow + 32;
    *(u16x8*)((char*)Ks + ((row2 * 128 + kc8 * 2) ^ ((row2 & 7) << 4))) = kr1;
    int sw = (vkey >> 3) & 1;
    char* vb = (char*)&Vs[t >> 6][0] + vkey * 32;
    *(u16x8*)(vb + sw * 16) = vr0;
    *(u16x8*)(vb + (1 - sw) * 16) = vr1;
  };

  const unsigned vs_base = (unsigned)(uintptr_t)(void*)&Vs[0][0];
  const unsigned tr_a = vs_base + (unsigned)((8 * g + (cc >> 2)) * 32 +
                                             (((cc & 2) >> 1) ^ (g & 1)) * 16 +
                                             (cc & 1) * 8);

  f32x4 oacc[4];
#pragma unroll
  for (int i = 0; i < 4; i++) oacc[i] = (f32x4){0.f, 0.f, 0.f, 0.f};
  float Mx[4] = {-1e30f, -1e30f, -1e30f, -1e30f};
  float Lx[4] = {0.f, 0.f, 0.f, 0.f};
  char* PsW = (char*)&Ps[w][0];

  issue_loads(0);
  for (int kt = 0; kt < S / 64; ++kt) {
    stage_lds();
    __syncthreads();
    if (kt + 1 < S / 64) issue_loads(kt + 1);

    f32x4 sacc[4];
#pragma unroll
    for (int nb = 0; nb < 4; nb++) sacc[nb] = (f32x4){0.f, 0.f, 0.f, 0.f};
#pragma unroll
    for (int nb = 0; nb < 4; nb++) {
      int key = nb * 16 + cc;
      int rb = key * 128, xr = (key & 7) << 4;
      bf16x8 k0 = lds_frag(Ks, (rb + g * 16) ^ xr);
      bf16x8 k1 = lds_frag(Ks, (rb + 64 + g * 16) ^ xr);
      sacc[nb] = MFMA_BF16(qa0, k0, sacc[nb]);
      sacc[nb] = MFMA_BF16(qa1, k1, sacc[nb]);
    }

    float sm[4] = {-1e30f, -1e30f, -1e30f, -1e30f};
#pragma unroll
    for (int nb = 0; nb < 4; nb++)
#pragma unroll
      for (int r4 = 0; r4 < 4; r4++) {
        float sv = sacc[nb][r4] * 0.125f;
        sv += res * __sinf(sv + ph);
        sacc[nb][r4] = sv;
        sm[r4] = fmaxf(sm[r4], sv);
      }
#pragma unroll
    for (int d = 1; d < 16; d <<= 1)
#pragma unroll
      for (int r4 = 0; r4 < 4; r4++) sm[r4] = fmaxf(sm[r4], __shfl_xor(sm[r4], d, 16));

    float alpha[4];
#pragma unroll
    for (int r4 = 0; r4 < 4; r4++) {
      float nm = fmaxf(Mx[r4], sm[r4]);
      alpha[r4] = __expf(Mx[r4] - nm);
      Mx[r4] = nm;
    }
#pragma unroll
    for (int nb = 0; nb < 4; nb++)
#pragma unroll
      for (int r4 = 0; r4 < 4; r4++) {
        float p = __expf(sacc[nb][r4] - Mx[r4]);
        int prow = g * 4 + r4, pcol = nb * 16 + cc;
        *(unsigned short*)(PsW + ((prow * 128 + pcol * 2) ^ ((prow & 7) << 4))) =
            f32_to_bf16(p);
      }

    bf16x8 pa0, pa1;
    {
      int xr = (cc & 7) << 4;
      pa0 = lds_frag((const unsigned short*)PsW, (cc * 128 + g * 16) ^ xr);
      pa1 = lds_frag((const unsigned short*)PsW, (cc * 128 + 64 + g * 16) ^ xr);
    }
    f32x4 pacc = (f32x4){0.f, 0.f, 0.f, 0.f};
    pacc = MFMA_BF16(pa0, ones8, pacc);
    pacc = MFMA_BF16(pa1, ones8, pacc);
#pragma unroll
    for (int r4 = 0; r4 < 4; r4++) Lx[r4] = Lx[r4] * alpha[r4] + pacc[r4];
#pragma unroll
    for (int nb2 = 0; nb2 < 4; nb2++)
#pragma unroll
      for (int r4 = 0; r4 < 4; r4++) oacc[nb2][r4] *= alpha[r4];

    u32x2 trv[4][4];
#pragma unroll
    for (int b2 = 0; b2 < 4; b2++) {
      unsigned a = tr_a + b2 * 2048;
      trv[b2][0] = tr_read(a);
      trv[b2][1] = tr_read(a + 128);
      trv[b2][2] = tr_read(a + 1024);
      trv[b2][3] = tr_read(a + 1152);
    }
    asm volatile("s_waitcnt lgkmcnt(0)" ::: "memory");
    __builtin_amdgcn_sched_barrier(0);
#pragma unroll
    for (int b2 = 0; b2 < 4; b2++) {
      bf16x8 v0 = __builtin_bit_cast(bf16x8,
          (u32x4){trv[b2][0][0], trv[b2][0][1], trv[b2][1][0], trv[b2][1][1]});
      bf16x8 v1 = __builtin_bit_cast(bf16x8,
          (u32x4){trv[b2][2][0], trv[b2][2][1], trv[b2][3][0], trv[b2][3][1]});
      oacc[b2] = MFMA_BF16(pa0, v0, oacc[b2]);
      oacc[b2] = MFMA_BF16(pa1, v1, oacc[b2]);
    }
    __syncthreads();
  }

#pragma unroll
  for (int nb2 = 0; nb2 < 4; nb2++)
#pragma unroll
    for (int r4 = 0; r4 < 4; r4++) {
      float ov = oacc[nb2][r4] / Lx[r4];
      O[(size_t)(b * S + q0 + g * 4 + r4) * ldo + h * 64 + nb2 * 16 + cc] = f32_to_bf16(ov);
    }
}

// ---------------------------------------------------------------------------
// y = harmonic_ln(xin + radd)
// ---------------------------------------------------------------------------
__global__ __launch_bounds__(256) void resid_harmonic_ln(const float* __restrict__ xin,
                                                         const float* __restrict__ radd,
                                                         const float* __restrict__ gamma,
                                                         const float* __restrict__ beta,
                                                         const float* __restrict__ stab,
                                                         float* __restrict__ yf,
                                                         unsigned short* __restrict__ yb) {
  const int row = blockIdx.x, t = threadIdx.x;
  const float* xr = xin + (size_t)row * 1024;
  const float* rr = radd + (size_t)row * 1024;
  float v[4], s = 0.f, ss = 0.f;
#pragma unroll
  for (int j = 0; j < 4; j++) {
    int idx = t + j * 256;
    v[j] = xr[idx] + rr[idx];
    s += v[j]; ss += v[j] * v[j];
  }
#pragma unroll
  for (int d = 1; d < 64; d <<= 1) { s += __shfl_xor(s, d); ss += __shfl_xor(ss, d); }
  __shared__ float sb[8];
  int lane = t & 63, wid = t >> 6;
  if (lane == 0) { sb[wid] = s; sb[4 + wid] = ss; }
  __syncthreads();
  s = sb[0] + sb[1] + sb[2] + sb[3];
  ss = sb[4] + sb[5] + sb[6] + sb[7];
  float mean = s * (1.f / 1024.f);
  float var = fmaxf((ss - 1024.f * mean * mean) * (1.f / 1023.f), 0.f);  // ddof=1
  float sd = sqrtf(var);
  sd += stab[0] * sinf(sd * 3.14159265358979323846f);
  float inv = 1.f / (sd + 1e-6f);
#pragma unroll
  for (int j = 0; j < 4; j++) {
    int idx = t + j * 256;
    float y = gamma[idx] * ((v[j] - mean) * inv) + beta[idx];
    yf[(size_t)row * 1024 + idx] = y;
    if (yb) yb[(size_t)row * 1024 + idx] = f32_to_bf16(y);
  }
}

// ---------------------------------------------------------------------------
extern "C" void kernel_launch(void* const* d_in, const int* in_sizes, int n_in,
                              void* d_out, int out_size, void* d_ws, size_t ws_size,
                              hipStream_t stream) {
  const float* x    = (const float*)d_in[0];
  const float* Wq   = (const float*)d_in[1];
  const float* bq   = (const float*)d_in[2];
  const float* Wk   = (const float*)d_in[3];
  const float* bk   = (const float*)d_in[4];
  const float* Wv   = (const float*)d_in[5];
  const float* bv   = (const float*)d_in[6];
  const float* Wo   = (const float*)d_in[7];
  const float* bo   = (const float*)d_in[8];
  const float* reso = (const float*)d_in[9];
  const float* phas = (const float*)d_in[10];
  const float* g1   = (const float*)d_in[11];
  const float* b1   = (const float*)d_in[12];
  const float* s1   = (const float*)d_in[13];
  const float* W1   = (const float*)d_in[14];
  const float* bf1  = (const float*)d_in[15];
  const float* W2   = (const float*)d_in[16];
  const float* bf2  = (const float*)d_in[17];
  const float* g2   = (const float*)d_in[18];
  const float* b2   = (const float*)d_in[19];
  const float* s2   = (const float*)d_in[20];

  const int BS = 4096;  // B*S

  char* ws = (char*)d_ws;
  const size_t OFF_QKV  = 0;                 // qkv bf16 [4096][3072]   25165824
  const size_t OFF_XB   = 25165824;          // xb bf16  [4096][1024]    8388608  (later: ao)
  const size_t OFF_WQKV = 33554432;          // Wqkv^T bf16 [3072][1024] 6291456
  const size_t OFF_WOT  = 39845888;          // Wo^T bf16 [1024][1024]   2097152
  const size_t OFF_W1T  = 41943040;          // W1^T bf16 [4096][1024]   8388608
  const size_t OFF_W2T  = 50331648;          // W2^T bf16 [1024][4096]   8388608
  const size_t OFF_BQKV = 58720256;          // bqkv f32 [3072]            12288
  const size_t OFF_T0   = 58736640;          // t0 f32 [4096][1024]     16777216
  const size_t OFF_X1   = 75513856;          // x1 f32 [4096][1024]     16777216
  const size_t OFF_X1B  = 92291072;          // x1b bf16 [4096][1024]    8388608
  // hb bf16 [4096][4096] = 33554432 @ offset 0 (over dead qkv+xb)

  unsigned short* qkv   = (unsigned short*)(ws + OFF_QKV);
  unsigned short* xb    = (unsigned short*)(ws + OFF_XB);
  unsigned short* ao    = (unsigned short*)(ws + OFF_XB);
  unsigned short* Wqkvt = (unsigned short*)(ws + OFF_WQKV);
  unsigned short* Wot   = (unsigned short*)(ws + OFF_WOT);
  unsigned short* W1t   = (unsigned short*)(ws + OFF_W1T);
  unsigned short* W2t   = (unsigned short*)(ws + OFF_W2T);
  float*          bqkv  = (float*)(ws + OFF_BQKV);
  float*          t0    = (float*)(ws + OFF_T0);
  float*          x1    = (float*)(ws + OFF_X1);
  unsigned short* x1b   = (unsigned short*)(ws + OFF_X1B);
  unsigned short* hb    = (unsigned short*)(ws + OFF_QKV);
  float*          out   = (float*)d_out;

  // 1. x -> bf16
  cvt_f32_bf16<<<4096, 256, 0, stream>>>(x, xb, BS * 1024);

  // 2. weight transposes (fp32 [K][N] -> bf16 [N][K])
  transpose_f32_bf16<<<dim3(32, 32), 256, 0, stream>>>(Wq, Wqkvt, 1024, 1024);
  transpose_f32_bf16<<<dim3(32, 32), 256, 0, stream>>>(Wk, Wqkvt + (size_t)1024 * 1024, 1024, 1024);
  transpose_f32_bf16<<<dim3(32, 32), 256, 0, stream>>>(Wv, Wqkvt + (size_t)2048 * 1024, 1024, 1024);
  transpose_f32_bf16<<<dim3(32, 32), 256, 0, stream>>>(Wo, Wot, 1024, 1024);
  transpose_f32_bf16<<<dim3(128, 32), 256, 0, stream>>>(W1, W1t, 1024, 4096);
  transpose_f32_bf16<<<dim3(32, 128), 256, 0, stream>>>(W2, W2t, 4096, 1024);

  // 3. pack qkv bias
  hipMemcpyAsync((void*)bqkv,          (const void*)bq, 1024 * 4, hipMemcpyDeviceToDevice, stream);
  hipMemcpyAsync((void*)(bqkv + 1024), (const void*)bk, 1024 * 4, hipMemcpyDeviceToDevice, stream);
  hipMemcpyAsync((void*)(bqkv + 2048), (const void*)bv, 1024 * 4, hipMemcpyDeviceToDevice, stream);

  // 4. fused QKV projection: [4096,1024] @ [1024,3072] -> bf16 qkv (256^2)
  gemm_bt8<0><<<dim3(12, 16), 512, 0, stream>>>(xb, Wqkvt, bqkv, qkv, nullptr,
                                                4096, 3072, 1024);

  // 5. attention -> ao bf16
  attn_fused<<<dim3(32, 32), 256, 0, stream>>>(qkv, qkv + 1024, qkv + 2048, 3072,
                                               reso, phas, ao, 1024);

  // 6. output projection -> t0 fp32 (2-phase, N=1024)
  gemm_bt<128, 64, 1><<<dim3(16, 32), 256, 0, stream>>>(ao, Wot, bo, nullptr, t0,
                                                        4096, 1024, 1024);

  // 7. x1 = harmonic_ln(x + attn_out)
  resid_harmonic_ln<<<4096, 256, 0, stream>>>(x, t0, g1, b1, s1, x1, x1b);

  // 8. FFN up + spectral activation -> hb bf16 (256^2)
  gemm_bt8<2><<<dim3(16, 16), 512, 0, stream>>>(x1b, W1t, bf1, hb, nullptr,
                                                4096, 4096, 1024);

  // 9. FFN down -> t0 fp32 (2-phase, N=1024)
  gemm_bt<128, 64, 1><<<dim3(16, 32), 256, 0, stream>>>(hb, W2t, bf2, nullptr, t0,
                                                        4096, 1024, 4096);

  // 10. out = harmonic_ln(x1 + ff)
  resid_harmonic_ln<<<4096, 256, 0, stream>>>(x1, t0, g2, b2, s2, out, nullptr);
}

// Round 9
// 486.238 us; speedup vs baseline: 1.0386x; 1.0386x over previous
//
#include <hip/hip_runtime.h>
#include <cstdint>
#include <cstddef>

// ---------------------------------------------------------------------------
// HarmonicTransformerLayer  B=2 S=2048 D=1024 H=16 HD=64 F=4096
// Round 9:
//   - gemm_bt8 rewritten as the TRUE fine-interleave 8-phase schedule
//     (m196/m201 template): per phase {ds_read frags || stage 1 half-tile}
//     -> s_barrier -> lgkmcnt(0) -> setprio+16 MFMA -> s_barrier;
//     vmcnt(2) only at phases 4/8. 2 K-tiles per iter, dbuf by parity.
//   - attn / gemm_bt / LN / transposes byte-identical to round 8
//     (attn doubles as cross-run clock reference).
// ---------------------------------------------------------------------------

typedef float  f32x4  __attribute__((ext_vector_type(4)));
typedef __bf16 bf16x8 __attribute__((ext_vector_type(8)));
typedef unsigned short u16x8 __attribute__((ext_vector_type(8)));
typedef unsigned short u16x4 __attribute__((ext_vector_type(4)));
typedef unsigned int   u32x2 __attribute__((ext_vector_type(2)));
typedef unsigned int   u32x4 __attribute__((ext_vector_type(4)));

#define MFMA_BF16(a, b, c) __builtin_amdgcn_mfma_f32_16x16x32_bf16((a), (b), (c), 0, 0, 0)

static __device__ __forceinline__ unsigned short f32_to_bf16(float f) {
  return __builtin_bit_cast(unsigned short, (__bf16)f);   // HW RNE cvt on gfx950
}
static __device__ __forceinline__ bf16x8 lds_frag(const unsigned short* base, int byte) {
  return __builtin_bit_cast(bf16x8, *(const u16x8*)((const char*)base + byte));
}
static __device__ __forceinline__ float spectral_act(float x) {
  const float c = 0.7978845608028654f;      // sqrt(2/pi)
  float g = 0.5f * x * (1.0f + tanhf(c * (x + 0.044715f * x * x * x)));
  return g + 0.5f * __sinf(x);              // ALPHA=0.5, BETA=1.0
}
static __device__ __forceinline__ void gload_lds16(const void* g, void* lds) {
  __builtin_amdgcn_global_load_lds((const __attribute__((address_space(1))) unsigned int*)g,
                                   (__attribute__((address_space(3))) unsigned int*)lds,
                                   16, 0, 0);
}
static __device__ __forceinline__ u32x2 tr_read(unsigned addr) {
  u32x2 r;
  asm volatile("ds_read_b64_tr_b16 %0, %1" : "=v"(r) : "v"(addr));
  return r;
}

// ---------------------------------------------------------------------------
// fp32 -> bf16 vector convert
// ---------------------------------------------------------------------------
__global__ __launch_bounds__(256) void cvt_f32_bf16(const float* __restrict__ in,
                                                    unsigned short* __restrict__ out, int n) {
  int i = (blockIdx.x * 256 + threadIdx.x) * 4;
  if (i < n) {
    float4 v = *(const float4*)(in + i);
    u16x4 o;
    o[0] = f32_to_bf16(v.x); o[1] = f32_to_bf16(v.y);
    o[2] = f32_to_bf16(v.z); o[3] = f32_to_bf16(v.w);
    *(u16x4*)(out + i) = o;
  }
}

// ---------------------------------------------------------------------------
// W [K][N] fp32  ->  Wt [N][K] bf16   (32x32 LDS tile transpose)
// ---------------------------------------------------------------------------
__global__ __launch_bounds__(256) void transpose_f32_bf16(const float* __restrict__ W,
                                                          unsigned short* __restrict__ Wt,
                                                          int K, int N) {
  __shared__ float tile[32][33];
  int tx = threadIdx.x & 31, ty = threadIdx.x >> 5;   // 32 x 8
  int k0 = blockIdx.y * 32, n0 = blockIdx.x * 32;
#pragma unroll
  for (int i = 0; i < 4; i++)
    tile[ty + i * 8][tx] = W[(size_t)(k0 + ty + i * 8) * N + n0 + tx];
  __syncthreads();
#pragma unroll
  for (int i = 0; i < 4; i++)
    Wt[(size_t)(n0 + ty + i * 8) * K + k0 + tx] = f32_to_bf16(tile[tx][ty + i * 8]);
}

// ---------------------------------------------------------------------------
// 8-wave 256^2 GEMM, fine-interleave 8-phase (m201 template, own ledger).
// BK=64; 512 threads = 8 waves (2M x 4N); per-wave tile 128x64 = acc[8][4].
// LDS 128KB As[2][256*64] Bs[2][256*64] (dbuf by K-tile parity); linear
// 128B rows, content chunk c at position c^(row&7) via pre-swizzled source.
// Iter j computes tiles t0=2j (P1-P4), t1=2j+1 (P5-P8). Stages (1 half-tile
// = 2 gload_lds/thread per phase):
//   P1:A1(t1) P2:B0(t1) P3:B1(t1) P4:A0(t0+2) P5:A1(t0+2) P6:B0(t0+2)
//   P7:B1(t0+2) P8:A0(t1+2)      [prologue: tile0 full + A0(tile1)]
// vmcnt(2) at P4/P8 (only the just-issued half outstanding), vmcnt(0) tail.
// Race audit: A(t) frags fully read by P3/P7 (both qm within wave's A-half);
// B(t) by P4/P8; stages of that region start strictly after the end barrier.
// ---------------------------------------------------------------------------
template <int EPI>
__global__ __launch_bounds__(512, 2) void gemm_bt8(const unsigned short* __restrict__ Ag,
                                                   const unsigned short* __restrict__ Bt,
                                                   const float* __restrict__ bias,
                                                   unsigned short* __restrict__ Cb,
                                                   float* __restrict__ Cf,
                                                   int M, int N, int K) {
  __shared__ unsigned short As[2][256 * 64];
  __shared__ unsigned short Bs[2][256 * 64];
  const int t = threadIdx.x;
  const int lane = t & 63, w = t >> 6;
  const int wr = w >> 2, wc = w & 3;            // 2 x 4 wave grid
  const int g = lane >> 4, cc = lane & 15;
  const int row0 = blockIdx.y * 256, col0 = blockIdx.x * 256;

  f32x4 acc[8][4];
#pragma unroll
  for (int mi = 0; mi < 8; mi++)
#pragma unroll
    for (int ni = 0; ni < 4; ni++) acc[mi][ni] = (f32x4){0.f, 0.f, 0.f, 0.f};

  const int nk = K >> 6;                         // 16 for K=1024
  const int sro8 = w * 8 + (lane >> 3);          // row within a 64-stripe
  const int sc8 = ((lane & 7) ^ ((lane >> 3) & 7)) * 8;   // src chunk (elems)

  // stage one half-tile (128 rows x 64 cols) = 2 gload_lds per thread
  auto stageA = [&](int buf, int kt, int h) {
#pragma unroll
    for (int i = 0; i < 2; ++i) {
      int rr = h * 128 + i * 64 + sro8;
      gload_lds16(Ag + (size_t)(row0 + rr) * K + (kt << 6) + sc8,
                  &As[buf][(h * 128 + i * 64 + w * 8) * 64]);
    }
  };
  auto stageB = [&](int buf, int kt, int h) {
#pragma unroll
    for (int i = 0; i < 2; ++i) {
      int rr = h * 128 + i * 64 + sro8;
      gload_lds16(Bt + (size_t)(col0 + rr) * K + (kt << 6) + sc8,
                  &Bs[buf][(h * 128 + i * 64 + w * 8) * 64]);
    }
  };
  auto rdA = [&](int buf, int qm, bf16x8 a[2][4]) {
#pragma unroll
    for (int ks = 0; ks < 2; ++ks)
#pragma unroll
      for (int i = 0; i < 4; ++i) {
        int r = wr * 128 + (qm * 4 + i) * 16 + cc;
        a[ks][i] = lds_frag(&As[buf][0], r * 128 + (((ks * 4 + g) ^ (cc & 7)) << 4));
      }
  };
  auto rdB = [&](int buf, int qn, bf16x8 bb[2][2]) {
#pragma unroll
    for (int ks = 0; ks < 2; ++ks)
#pragma unroll
      for (int j = 0; j < 2; ++j) {
        int r = wc * 64 + (qn * 2 + j) * 16 + cc;
        bb[ks][j] = lds_frag(&Bs[buf][0], r * 128 + (((ks * 4 + g) ^ (cc & 7)) << 4));
      }
  };
  auto mma = [&](int qm, int qn, bf16x8 a[2][4], bf16x8 bb[2][2]) {
    __builtin_amdgcn_s_setprio(1);
#pragma unroll
    for (int ks = 0; ks < 2; ++ks)
#pragma unroll
      for (int i = 0; i < 4; ++i)
#pragma unroll
        for (int j = 0; j < 2; ++j)
          acc[qm * 4 + i][qn * 2 + j] =
              MFMA_BF16(a[ks][i], bb[ks][j], acc[qm * 4 + i][qn * 2 + j]);
    __builtin_amdgcn_s_setprio(0);
  };

#define SYNC_IN()  do { asm volatile("s_barrier" ::: "memory");               \
                        asm volatile("s_waitcnt lgkmcnt(0)" ::: "memory");    \
                        __builtin_amdgcn_sched_barrier(0); } while (0)
#define SYNC_OUT() asm volatile("s_barrier" ::: "memory")

  // ---- prologue: tile0 full + A0(tile1) ----
  stageA(0, 0, 0); stageA(0, 0, 1); stageB(0, 0, 0); stageB(0, 0, 1);
  if (nk > 1) {
    stageA(1, 1, 0);
    asm volatile("s_waitcnt vmcnt(2)" ::: "memory");   // tile0 landed
  } else {
    asm volatile("s_waitcnt vmcnt(0)" ::: "memory");
  }
  asm volatile("s_barrier" ::: "memory");

  const int niter = nk >> 1;
  for (int j = 0; j < niter; ++j) {
    const int t0 = 2 * j, t1 = 2 * j + 1;
    const bool s0 = (t0 + 2 < nk), s1 = (t1 + 2 < nk);
    bf16x8 a[2][4], bb0[2][2], bb1[2][2];

    // ---- P1: q(0,0) of t0 ----
    rdA(0, 0, a); rdB(0, 0, bb0);
    stageA(1, t1, 1);
    SYNC_IN(); mma(0, 0, a, bb0); SYNC_OUT();
    // ---- P2: q(0,1) of t0 ----
    rdB(0, 1, bb1);
    stageB(1, t1, 0);
    SYNC_IN(); mma(0, 1, a, bb1); SYNC_OUT();
    // ---- P3: q(1,1) of t0 ----
    rdA(0, 1, a);
    stageB(1, t1, 1);
    SYNC_IN(); mma(1, 1, a, bb1); SYNC_OUT();
    // ---- P4: q(1,0) of t0 ----
    rdB(0, 0, bb0);
    if (s0) { stageA(0, t0 + 2, 0); asm volatile("s_waitcnt vmcnt(2)" ::: "memory"); }
    else    {                       asm volatile("s_waitcnt vmcnt(0)" ::: "memory"); }
    SYNC_IN(); mma(1, 0, a, bb0); SYNC_OUT();

    // ---- P5: q(0,0) of t1 ----
    rdA(1, 0, a); rdB(1, 0, bb0);
    if (s0) stageA(0, t0 + 2, 1);
    SYNC_IN(); mma(0, 0, a, bb0); SYNC_OUT();
    // ---- P6: q(0,1) of t1 ----
    rdB(1, 1, bb1);
    if (s0) stageB(0, t0 + 2, 0);
    SYNC_IN(); mma(0, 1, a, bb1); SYNC_OUT();
    // ---- P7: q(1,1) of t1 ----
    rdA(1, 1, a);
    if (s0) stageB(0, t0 + 2, 1);
    SYNC_IN(); mma(1, 1, a, bb1); SYNC_OUT();
    // ---- P8: q(1,0) of t1 ----
    rdB(1, 0, bb0);
    if (s1) { stageA(1, t1 + 2, 0); asm volatile("s_waitcnt vmcnt(2)" ::: "memory"); }
    SYNC_IN(); mma(1, 0, a, bb0); SYNC_OUT();
  }
#undef SYNC_IN
#undef SYNC_OUT

  // ---- epilogue ----
#pragma unroll
  for (int mi = 0; mi < 8; ++mi) {
#pragma unroll
    for (int ni = 0; ni < 4; ++ni) {
      int col = col0 + wc * 64 + ni * 16 + cc;
      float bv = bias[col];
#pragma unroll
      for (int r4 = 0; r4 < 4; r4++) {
        int row = row0 + wr * 128 + mi * 16 + g * 4 + r4;
        float val = acc[mi][ni][r4] + bv;
        if (EPI == 2) val = spectral_act(val);
        if (EPI == 0 || EPI == 2) Cb[(size_t)row * N + col] = f32_to_bf16(val);
        else                      Cf[(size_t)row * N + col] = val;
      }
    }
  }
}

// ---------------------------------------------------------------------------
// 2-phase 128-tile GEMM (round-5) for N=1024 outputs (Wo, FFN-down).
// ---------------------------------------------------------------------------
template <int BM, int BN, int EPI>
__global__ __launch_bounds__(256) void gemm_bt(const unsigned short* __restrict__ A,
                                               const unsigned short* __restrict__ Bt,
                                               const float* __restrict__ bias,
                                               unsigned short* __restrict__ Cb,
                                               float* __restrict__ Cf,
                                               int M, int N, int K) {
  constexpr int MI = BM / 32;
  constexpr int NI = BN / 32;
  __shared__ unsigned short As[2][BM * 32];
  __shared__ unsigned short Bs[2][BN * 32];
  const int t = threadIdx.x;
  const int lane = t & 63, w = t >> 6;
  const int wr = w >> 1, wc = w & 1;
  const int g = lane >> 4, cc = lane & 15;
  const int row0 = blockIdx.y * BM, col0 = blockIdx.x * BN;

  f32x4 acc[MI][NI];
#pragma unroll
  for (int mi = 0; mi < MI; mi++)
#pragma unroll
    for (int ni = 0; ni < NI; ni++) acc[mi][ni] = (f32x4){0.f, 0.f, 0.f, 0.f};

  const int nk = K >> 5;
  const int srow = lane >> 2;
  const int schunk = (lane & 3) ^ (srow & 3);

  auto stage = [&](int buf, int kt) {
#pragma unroll
    for (int i = 0; i < BM / 64; ++i) {
      int r = i * 64 + w * 16;
      gload_lds16(A + (size_t)(row0 + r + srow) * K + (kt << 5) + schunk * 8,
                  &As[buf][r * 32]);
    }
#pragma unroll
    for (int i = 0; i < BN / 64; ++i) {
      int r = i * 64 + w * 16;
      gload_lds16(Bt + (size_t)(col0 + r + srow) * K + (kt << 5) + schunk * 8,
                  &Bs[buf][r * 32]);
    }
  };

  stage(0, 0);
  __syncthreads();
  int cur = 0;
  for (int kt = 0; kt < nk; ++kt) {
    if (kt + 1 < nk) stage(cur ^ 1, kt + 1);

    bf16x8 af[MI], bg[NI];
#pragma unroll
    for (int mi = 0; mi < MI; mi++) {
      int r = wr * (BM / 2) + mi * 16 + cc;
      af[mi] = lds_frag(&As[cur][0], r * 64 + ((g ^ (cc & 3)) << 4));
    }
#pragma unroll
    for (int ni = 0; ni < NI; ni++) {
      int r = wc * (BN / 2) + ni * 16 + cc;
      bg[ni] = lds_frag(&Bs[cur][0], r * 64 + ((g ^ (cc & 3)) << 4));
    }
#pragma unroll
    for (int mi = 0; mi < MI; mi++)
#pragma unroll
      for (int ni = 0; ni < NI; ni++)
        acc[mi][ni] = MFMA_BF16(af[mi], bg[ni], acc[mi][ni]);

    __syncthreads();
    cur ^= 1;
  }

#pragma unroll
  for (int mi = 0; mi < MI; mi++) {
#pragma unroll
    for (int ni = 0; ni < NI; ni++) {
      int col = col0 + wc * (BN / 2) + ni * 16 + cc;
      float bv = bias[col];
#pragma unroll
      for (int r4 = 0; r4 < 4; r4++) {
        int row = row0 + wr * (BM / 2) + mi * 16 + g * 4 + r4;
        float val = acc[mi][ni][r4] + bv;
        if (EPI == 2) val = spectral_act(val);
        if (EPI == 0 || EPI == 2) Cb[(size_t)row * N + col] = f32_to_bf16(val);
        else                      Cf[(size_t)row * N + col] = val;
      }
    }
  }
}

// ---------------------------------------------------------------------------
// Flash attention with harmonic score modification (round-5, T14 split).
// Byte-identical to round 8 (serves as cross-run clock reference).
// ---------------------------------------------------------------------------
__global__ __launch_bounds__(256) void attn_fused(const unsigned short* __restrict__ Qb,
                                                  const unsigned short* __restrict__ Kb,
                                                  const unsigned short* __restrict__ Vb,
                                                  int ld,
                                                  const float* __restrict__ resonance,
                                                  const float* __restrict__ phase,
                                                  unsigned short* __restrict__ O, int ldo) {
  constexpr int S = 2048;
  __shared__ unsigned short Ks[64 * 64];
  __shared__ unsigned short Vs[4][64 * 16];
  __shared__ unsigned short Ps[4][16 * 64];

  const int t = threadIdx.x, lane = t & 63, w = t >> 6;
  const int g = lane >> 4, cc = lane & 15;
  const int bh = blockIdx.y, b = bh >> 4, h = bh & 15;
  const int q0 = blockIdx.x * 64 + w * 16;
  const float res = resonance[h], ph = phase[h];

  const unsigned short* Qh = Qb + (size_t)b * S * ld + h * 64;
  const unsigned short* Kh = Kb + (size_t)b * S * ld + h * 64;
  const unsigned short* Vh = Vb + (size_t)b * S * ld + h * 64;

  bf16x8 qa0, qa1;
  {
    const unsigned short* qp = Qh + (size_t)(q0 + cc) * ld + g * 8;
    qa0 = __builtin_bit_cast(bf16x8, *(const u16x8*)qp);
    qa1 = __builtin_bit_cast(bf16x8, *(const u16x8*)(qp + 32));
  }

  bf16x8 ones8;
#pragma unroll
  for (int j = 0; j < 8; j++) ones8[j] = (__bf16)1.0f;

  const int krow = t >> 3, kc8 = (t & 7) * 8;
  const int vkey = t & 63, vb0 = (t >> 6) * 16;
  u16x8 kr0, kr1, vr0, vr1;

  auto issue_loads = [&](int kt) {
    const unsigned short* kp = Kh + (size_t)(kt * 64) * ld;
    kr0 = *(const u16x8*)(kp + (size_t)krow * ld + kc8);
    kr1 = *(const u16x8*)(kp + (size_t)(krow + 32) * ld + kc8);
    const unsigned short* vp = Vh + (size_t)(kt * 64 + vkey) * ld + vb0;
    vr0 = *(const u16x8*)vp;
    vr1 = *(const u16x8*)(vp + 8);
  };
  auto stage_lds = [&]() {
    *(u16x8*)((char*)Ks + ((krow * 128 + kc8 * 2) ^ ((krow & 7) << 4))) = kr0;
    int row2 = krow + 32;
    *(u16x8*)((char*)Ks + ((row2 * 128 + kc8 * 2) ^ ((row2 & 7) << 4))) = kr1;
    int sw = (vkey >> 3) & 1;
    char* vb = (char*)&Vs[t >> 6][0] + vkey * 32;
    *(u16x8*)(vb + sw * 16) = vr0;
    *(u16x8*)(vb + (1 - sw) * 16) = vr1;
  };

  const unsigned vs_base = (unsigned)(uintptr_t)(void*)&Vs[0][0];
  const unsigned tr_a = vs_base + (unsigned)((8 * g + (cc >> 2)) * 32 +
                                             (((cc & 2) >> 1) ^ (g & 1)) * 16 +
                                             (cc & 1) * 8);

  f32x4 oacc[4];
#pragma unroll
  for (int i = 0; i < 4; i++) oacc[i] = (f32x4){0.f, 0.f, 0.f, 0.f};
  float Mx[4] = {-1e30f, -1e30f, -1e30f, -1e30f};
  float Lx[4] = {0.f, 0.f, 0.f, 0.f};
  char* PsW = (char*)&Ps[w][0];

  issue_loads(0);
  for (int kt = 0; kt < S / 64; ++kt) {
    stage_lds();
    __syncthreads();
    if (kt + 1 < S / 64) issue_loads(kt + 1);

    f32x4 sacc[4];
#pragma unroll
    for (int nb = 0; nb < 4; nb++) sacc[nb] = (f32x4){0.f, 0.f, 0.f, 0.f};
#pragma unroll
    for (int nb = 0; nb < 4; nb++) {
      int key = nb * 16 + cc;
      int rb = key * 128, xr = (key & 7) << 4;
      bf16x8 k0 = lds_frag(Ks, (rb + g * 16) ^ xr);
      bf16x8 k1 = lds_frag(Ks, (rb + 64 + g * 16) ^ xr);
      sacc[nb] = MFMA_BF16(qa0, k0, sacc[nb]);
      sacc[nb] = MFMA_BF16(qa1, k1, sacc[nb]);
    }

    float sm[4] = {-1e30f, -1e30f, -1e30f, -1e30f};
#pragma unroll
    for (int nb = 0; nb < 4; nb++)
#pragma unroll
      for (int r4 = 0; r4 < 4; r4++) {
        float sv = sacc[nb][r4] * 0.125f;
        sv += res * __sinf(sv + ph);
        sacc[nb][r4] = sv;
        sm[r4] = fmaxf(sm[r4], sv);
      }
#pragma unroll
    for (int d = 1; d < 16; d <<= 1)
#pragma unroll
      for (int r4 = 0; r4 < 4; r4++) sm[r4] = fmaxf(sm[r4], __shfl_xor(sm[r4], d, 16));

    float alpha[4];
#pragma unroll
    for (int r4 = 0; r4 < 4; r4++) {
      float nm = fmaxf(Mx[r4], sm[r4]);
      alpha[r4] = __expf(Mx[r4] - nm);
      Mx[r4] = nm;
    }
#pragma unroll
    for (int nb = 0; nb < 4; nb++)
#pragma unroll
      for (int r4 = 0; r4 < 4; r4++) {
        float p = __expf(sacc[nb][r4] - Mx[r4]);
        int prow = g * 4 + r4, pcol = nb * 16 + cc;
        *(unsigned short*)(PsW + ((prow * 128 + pcol * 2) ^ ((prow & 7) << 4))) =
            f32_to_bf16(p);
      }

    bf16x8 pa0, pa1;
    {
      int xr = (cc & 7) << 4;
      pa0 = lds_frag((const unsigned short*)PsW, (cc * 128 + g * 16) ^ xr);
      pa1 = lds_frag((const unsigned short*)PsW, (cc * 128 + 64 + g * 16) ^ xr);
    }
    f32x4 pacc = (f32x4){0.f, 0.f, 0.f, 0.f};
    pacc = MFMA_BF16(pa0, ones8, pacc);
    pacc = MFMA_BF16(pa1, ones8, pacc);
#pragma unroll
    for (int r4 = 0; r4 < 4; r4++) Lx[r4] = Lx[r4] * alpha[r4] + pacc[r4];
#pragma unroll
    for (int nb2 = 0; nb2 < 4; nb2++)
#pragma unroll
      for (int r4 = 0; r4 < 4; r4++) oacc[nb2][r4] *= alpha[r4];

    u32x2 trv[4][4];
#pragma unroll
    for (int b2 = 0; b2 < 4; b2++) {
      unsigned a = tr_a + b2 * 2048;
      trv[b2][0] = tr_read(a);
      trv[b2][1] = tr_read(a + 128);
      trv[b2][2] = tr_read(a + 1024);
      trv[b2][3] = tr_read(a + 1152);
    }
    asm volatile("s_waitcnt lgkmcnt(0)" ::: "memory");
    __builtin_amdgcn_sched_barrier(0);
#pragma unroll
    for (int b2 = 0; b2 < 4; b2++) {
      bf16x8 v0 = __builtin_bit_cast(bf16x8,
          (u32x4){trv[b2][0][0], trv[b2][0][1], trv[b2][1][0], trv[b2][1][1]});
      bf16x8 v1 = __builtin_bit_cast(bf16x8,
          (u32x4){trv[b2][2][0], trv[b2][2][1], trv[b2][3][0], trv[b2][3][1]});
      oacc[b2] = MFMA_BF16(pa0, v0, oacc[b2]);
      oacc[b2] = MFMA_BF16(pa1, v1, oacc[b2]);
    }
    __syncthreads();
  }

#pragma unroll
  for (int nb2 = 0; nb2 < 4; nb2++)
#pragma unroll
    for (int r4 = 0; r4 < 4; r4++) {
      float ov = oacc[nb2][r4] / Lx[r4];
      O[(size_t)(b * S + q0 + g * 4 + r4) * ldo + h * 64 + nb2 * 16 + cc] = f32_to_bf16(ov);
    }
}

// ---------------------------------------------------------------------------
// y = harmonic_ln(xin + radd)
// ---------------------------------------------------------------------------
__global__ __launch_bounds__(256) void resid_harmonic_ln(const float* __restrict__ xin,
                                                         const float* __restrict__ radd,
                                                         const float* __restrict__ gamma,
                                                         const float* __restrict__ beta,
                                                         const float* __restrict__ stab,
                                                         float* __restrict__ yf,
                                                         unsigned short* __restrict__ yb) {
  const int row = blockIdx.x, t = threadIdx.x;
  const float* xr = xin + (size_t)row * 1024;
  const float* rr = radd + (size_t)row * 1024;
  float v[4], s = 0.f, ss = 0.f;
#pragma unroll
  for (int j = 0; j < 4; j++) {
    int idx = t + j * 256;
    v[j] = xr[idx] + rr[idx];
    s += v[j]; ss += v[j] * v[j];
  }
#pragma unroll
  for (int d = 1; d < 64; d <<= 1) { s += __shfl_xor(s, d); ss += __shfl_xor(ss, d); }
  __shared__ float sb[8];
  int lane = t & 63, wid = t >> 6;
  if (lane == 0) { sb[wid] = s; sb[4 + wid] = ss; }
  __syncthreads();
  s = sb[0] + sb[1] + sb[2] + sb[3];
  ss = sb[4] + sb[5] + sb[6] + sb[7];
  float mean = s * (1.f / 1024.f);
  float var = fmaxf((ss - 1024.f * mean * mean) * (1.f / 1023.f), 0.f);  // ddof=1
  float sd = sqrtf(var);
  sd += stab[0] * sinf(sd * 3.14159265358979323846f);
  float inv = 1.f / (sd + 1e-6f);
#pragma unroll
  for (int j = 0; j < 4; j++) {
    int idx = t + j * 256;
    float y = gamma[idx] * ((v[j] - mean) * inv) + beta[idx];
    yf[(size_t)row * 1024 + idx] = y;
    if (yb) yb[(size_t)row * 1024 + idx] = f32_to_bf16(y);
  }
}

// ---------------------------------------------------------------------------
extern "C" void kernel_launch(void* const* d_in, const int* in_sizes, int n_in,
                              void* d_out, int out_size, void* d_ws, size_t ws_size,
                              hipStream_t stream) {
  const float* x    = (const float*)d_in[0];
  const float* Wq   = (const float*)d_in[1];
  const float* bq   = (const float*)d_in[2];
  const float* Wk   = (const float*)d_in[3];
  const float* bk   = (const float*)d_in[4];
  const float* Wv   = (const float*)d_in[5];
  const float* bv   = (const float*)d_in[6];
  const float* Wo   = (const float*)d_in[7];
  const float* bo   = (const float*)d_in[8];
  const float* reso = (const float*)d_in[9];
  const float* phas = (const float*)d_in[10];
  const float* g1   = (const float*)d_in[11];
  const float* b1   = (const float*)d_in[12];
  const float* s1   = (const float*)d_in[13];
  const float* W1   = (const float*)d_in[14];
  const float* bf1  = (const float*)d_in[15];
  const float* W2   = (const float*)d_in[16];
  const float* bf2  = (const float*)d_in[17];
  const float* g2   = (const float*)d_in[18];
  const float* b2   = (const float*)d_in[19];
  const float* s2   = (const float*)d_in[20];

  const int BS = 4096;  // B*S

  char* ws = (char*)d_ws;
  const size_t OFF_QKV  = 0;                 // qkv bf16 [4096][3072]   25165824
  const size_t OFF_XB   = 25165824;          // xb bf16  [4096][1024]    8388608  (later: ao)
  const size_t OFF_WQKV = 33554432;          // Wqkv^T bf16 [3072][1024] 6291456
  const size_t OFF_WOT  = 39845888;          // Wo^T bf16 [1024][1024]   2097152
  const size_t OFF_W1T  = 41943040;          // W1^T bf16 [4096][1024]   8388608
  const size_t OFF_W2T  = 50331648;          // W2^T bf16 [1024][4096]   8388608
  const size_t OFF_BQKV = 58720256;          // bqkv f32 [3072]            12288
  const size_t OFF_T0   = 58736640;          // t0 f32 [4096][1024]     16777216
  const size_t OFF_X1   = 75513856;          // x1 f32 [4096][1024]     16777216
  const size_t OFF_X1B  = 92291072;          // x1b bf16 [4096][1024]    8388608
  // hb bf16 [4096][4096] = 33554432 @ offset 0 (over dead qkv+xb)

  unsigned short* qkv   = (unsigned short*)(ws + OFF_QKV);
  unsigned short* xb    = (unsigned short*)(ws + OFF_XB);
  unsigned short* ao    = (unsigned short*)(ws + OFF_XB);
  unsigned short* Wqkvt = (unsigned short*)(ws + OFF_WQKV);
  unsigned short* Wot   = (unsigned short*)(ws + OFF_WOT);
  unsigned short* W1t   = (unsigned short*)(ws + OFF_W1T);
  unsigned short* W2t   = (unsigned short*)(ws + OFF_W2T);
  float*          bqkv  = (float*)(ws + OFF_BQKV);
  float*          t0    = (float*)(ws + OFF_T0);
  float*          x1    = (float*)(ws + OFF_X1);
  unsigned short* x1b   = (unsigned short*)(ws + OFF_X1B);
  unsigned short* hb    = (unsigned short*)(ws + OFF_QKV);
  float*          out   = (float*)d_out;

  // 1. x -> bf16
  cvt_f32_bf16<<<4096, 256, 0, stream>>>(x, xb, BS * 1024);

  // 2. weight transposes (fp32 [K][N] -> bf16 [N][K])
  transpose_f32_bf16<<<dim3(32, 32), 256, 0, stream>>>(Wq, Wqkvt, 1024, 1024);
  transpose_f32_bf16<<<dim3(32, 32), 256, 0, stream>>>(Wk, Wqkvt + (size_t)1024 * 1024, 1024, 1024);
  transpose_f32_bf16<<<dim3(32, 32), 256, 0, stream>>>(Wv, Wqkvt + (size_t)2048 * 1024, 1024, 1024);
  transpose_f32_bf16<<<dim3(32, 32), 256, 0, stream>>>(Wo, Wot, 1024, 1024);
  transpose_f32_bf16<<<dim3(128, 32), 256, 0, stream>>>(W1, W1t, 1024, 4096);
  transpose_f32_bf16<<<dim3(32, 128), 256, 0, stream>>>(W2, W2t, 4096, 1024);

  // 3. pack qkv bias
  hipMemcpyAsync((void*)bqkv,          (const void*)bq, 1024 * 4, hipMemcpyDeviceToDevice, stream);
  hipMemcpyAsync((void*)(bqkv + 1024), (const void*)bk, 1024 * 4, hipMemcpyDeviceToDevice, stream);
  hipMemcpyAsync((void*)(bqkv + 2048), (const void*)bv, 1024 * 4, hipMemcpyDeviceToDevice, stream);

  // 4. fused QKV projection: [4096,1024] @ [1024,3072] -> bf16 qkv (8-phase)
  gemm_bt8<0><<<dim3(12, 16), 512, 0, stream>>>(xb, Wqkvt, bqkv, qkv, nullptr,
                                                4096, 3072, 1024);

  // 5. attention -> ao bf16
  attn_fused<<<dim3(32, 32), 256, 0, stream>>>(qkv, qkv + 1024, qkv + 2048, 3072,
                                               reso, phas, ao, 1024);

  // 6. output projection -> t0 fp32 (2-phase, N=1024)
  gemm_bt<128, 64, 1><<<dim3(16, 32), 256, 0, stream>>>(ao, Wot, bo, nullptr, t0,
                                                        4096, 1024, 1024);

  // 7. x1 = harmonic_ln(x + attn_out)
  resid_harmonic_ln<<<4096, 256, 0, stream>>>(x, t0, g1, b1, s1, x1, x1b);

  // 8. FFN up + spectral activation -> hb bf16 (8-phase)
  gemm_bt8<2><<<dim3(16, 16), 512, 0, stream>>>(x1b, W1t, bf1, hb, nullptr,
                                                4096, 4096, 1024);

  // 9. FFN down -> t0 fp32 (2-phase, N=1024)
  gemm_bt<128, 64, 1><<<dim3(16, 32), 256, 0, stream>>>(hb, W2t, bf2, nullptr, t0,
                                                        4096, 1024, 4096);

  // 10. out = harmonic_ln(x1 + ff)
  resid_harmonic_ln<<<4096, 256, 0, stream>>>(x1, t0, g2, b2, s2, out, nullptr);
}